// Round 9
// baseline (255.989 us; speedup 1.0000x reference)
//
#include <hip/hip_runtime.h>

typedef short bf16x8 __attribute__((ext_vector_type(8)));
typedef float f32x4 __attribute__((ext_vector_type(4)));

#define NTOK 262144
#define HH 100
#define DW 100
#define DT 25
#define KK 125
#define HSTR 52   // hstage dword stride: quad-stride 13 (odd) -> even LDS bank windows

__device__ __forceinline__ short f2bf(float f) {
    union { float f; unsigned u; } v; v.f = f;
    unsigned u = v.u + 0x7FFFu + ((v.u >> 16) & 1u);   // RNE bf16 (inputs finite)
    return (short)(u >> 16);
}

__device__ __forceinline__ float sigm(float x) {
    return __builtin_amdgcn_rcpf(1.f + __expf(-x));
}
__device__ __forceinline__ float tanh_(float x) {
    return 2.f * __builtin_amdgcn_rcpf(1.f + __expf(-2.f * x)) - 1.f;
}

// ---------------- pre-kernel: build B fragments + folded biases in ws ----------------
// bfrag layout: [sid(14 = d*7+jt)][fid(12 = gt*4+ks)][lane(64)] bf16x8  (= 172032 B)
// bias3 layout: [d(2)][gt(3)][jpad(112)] float                          (= 2688 B)
__global__ __launch_bounds__(256)
void build_b(const float* __restrict__ Wf, const float* __restrict__ bif, const float* __restrict__ bhf,
             const float* __restrict__ Wb, const float* __restrict__ bib, const float* __restrict__ bhb,
             bf16x8* __restrict__ bfrag, float* __restrict__ bias3)
{
    const int gwid = (blockIdx.x * 256 + threadIdx.x) >> 6;   // 0..167
    const int lane = threadIdx.x & 63;
    if (gwid >= 168) return;
    const int d   = gwid / 84;
    const int rem = gwid % 84;           // jt*12 + fid
    const int jt  = rem / 12, fid = rem % 12;
    const int gt  = fid >> 2, ks = fid & 3;
    const int l15 = lane & 15, lg = lane >> 4;
    const int j = jt * 16 + l15;
    const bool jv = (j < HH);
    const float* W = d ? Wb : Wf;
    const int gbase = (gt == 0) ? 0 : (gt == 1) ? 2 * HH : 3 * HH;   // i, g, o (f dead: c0==0)
    const float* wrow = W + (size_t)(gbase + (jv ? j : 0)) * KK;
    bf16x8 f;
    #pragma unroll
    for (int e = 0; e < 8; ++e) {
        const int k = ks * 32 + lg * 8 + e;
        const float v = (jv && k < KK) ? wrow[k] : 0.f;
        f[e] = f2bf(v);
    }
    bfrag[(size_t)gwid * 64 + lane] = f;
    if (ks == 0 && lg == 0) {
        const float* bi = d ? bib : bif;
        const float* bh = d ? bhb : bhf;
        bias3[(d * 3 + gt) * 112 + jt * 16 + l15] =
            jv ? (bi[gbase + j] + bh[gbase + j]) : 0.f;
    }
}

// ---------------- main kernel: ZERO barriers, mt-fused W streaming ----------------
// 4 waves x 32 tokens per block (128 tokens), grid 2048; waves fully independent.
// W fragments streamed per-wave from L2-resident bfrag, read ONCE per (d,jt)
// and reused across both 16-token M-tiles (R8's LDS slab re-reads deleted:
// 474 -> ~54 LDS ops/wave). hstage shrunk to one reused [32][52] buffer per
// wave (26.6 KB/block) via j-split double flush: j[0,48) after jt=2,
// j[48,100) after jt=6 -> occupancy capped by VGPR (~16-20 waves/CU), not LDS.
__global__ __launch_bounds__(256, 5)
void lstm_main(const int* __restrict__ sent, const int* __restrict__ tags,
               const float* __restrict__ Ew, const float* __restrict__ Et,
               const bf16x8* __restrict__ bfrag, const float* __restrict__ bias3,
               float* __restrict__ out)
{
    __shared__ float hstage[4][32 * HSTR];   // 26624 B total
    const int tid  = threadIdx.x;
    const int lane = tid & 63;
    const int wave = tid >> 6;
    const int l15  = lane & 15;        // token within 16-tile
    const int lg   = lane >> 4;        // k-group (inputs) / j-quad (output)
    const int kb0  = lg * 8;
    const int tok_base = blockIdx.x * 128 + wave * 32;

    // ---- gather x fragments (MFMA B-operand): x = [E_w row | E_t row | pad] ----
    bf16x8 a[2][4];
    #pragma unroll
    for (int mt = 0; mt < 2; ++mt) {
        const int tok = tok_base + mt * 16 + l15;
        const float* ew = Ew + (size_t)sent[tok] * DW;
        const float* et = Et + (size_t)tags[tok] * DT;
        #pragma unroll
        for (int ks = 0; ks < 3; ++ks) {          // k in [0,96): pure E_w, 16B-aligned
            const float* p = ew + ks * 32 + kb0;
            const float4 v0 = *(const float4*)p;
            const float4 v1 = *(const float4*)(p + 4);
            bf16x8 f;
            f[0] = f2bf(v0.x); f[1] = f2bf(v0.y); f[2] = f2bf(v0.z); f[3] = f2bf(v0.w);
            f[4] = f2bf(v1.x); f[5] = f2bf(v1.y); f[6] = f2bf(v1.z); f[7] = f2bf(v1.w);
            a[mt][ks] = f;
        }
        {   // ks == 3: k in [96,128) -> E_w tail / E_t / zero pad
            float v[8];
            if (lg == 0) {
                const float4 w = *(const float4*)(ew + 96);
                v[0] = w.x; v[1] = w.y; v[2] = w.z; v[3] = w.w;
                #pragma unroll
                for (int e = 0; e < 4; ++e) v[4 + e] = et[e];
            } else {
                const int base = lg * 8 - 4;       // E_t index of elem 0
                #pragma unroll
                for (int e = 0; e < 8; ++e) {
                    const int ti = base + e;
                    v[e] = (ti < DT) ? et[ti] : 0.f;
                }
            }
            bf16x8 f;
            #pragma unroll
            for (int e = 0; e < 8; ++e) f[e] = f2bf(v[e]);
            a[mt][3] = f;
        }
    }

    float* hs = hstage[wave];

    for (int d = 0; d < 2; ++d) {
        #pragma unroll
        for (int jt = 0; jt < 7; ++jt) {
            // 12 coalesced 1KB loads from L2-resident bfrag, used for BOTH mt
            const bf16x8* bp = bfrag + ((size_t)(d * 7 + jt) * 12) * 64 + lane;
            bf16x8 b[12];
            #pragma unroll
            for (int f = 0; f < 12; ++f) b[f] = bp[(size_t)f * 64];

            f32x4 acc[2][3];
            #pragma unroll
            for (int gt = 0; gt < 3; ++gt) {
                // bias pre-folded into accumulator init (row = j = jt*16+lg*4+r)
                const f32x4 bv = *(const f32x4*)&bias3[(size_t)(d * 3 + gt) * 112 + jt * 16 + lg * 4];
                acc[0][gt] = bv;
                acc[1][gt] = bv;
                #pragma unroll
                for (int mt = 0; mt < 2; ++mt)
                    #pragma unroll
                    for (int ks = 0; ks < 4; ++ks)
                        acc[mt][gt] = __builtin_amdgcn_mfma_f32_16x16x32_bf16(
                            b[gt * 4 + ks], a[mt][ks], acc[mt][gt], 0, 0, 0);
            }

            const bool sv = (jt < 6) || (lg == 0);   // j-quad valid (j<100)
            if (sv) {
                // hstage column: j-split halves both map to col in [0,52)
                const int col = (jt < 3 ? jt * 16 : (jt - 3) * 16) + lg * 4;
                #pragma unroll
                for (int mt = 0; mt < 2; ++mt) {
                    f32x4 h;
                    #pragma unroll
                    for (int r = 0; r < 4; ++r) {
                        const float c = sigm(acc[mt][0][r]) * tanh_(acc[mt][1][r]);
                        h[r] = sigm(acc[mt][2][r]) * tanh_(c);
                    }
                    *(f32x4*)&hs[(mt * 16 + l15) * HSTR + col] = h;
                }
            }

            if (jt == 2) {
                // flush1: j in [0,48) x 32 tokens = 1536 dwords, 6 full wave-stores
                float* dst = out + (size_t)tok_base * 200 + d * 100;
                #pragma unroll
                for (int it = 0; it < 6; ++it) {
                    const int fd = it * 256 + lane * 4;
                    const int t  = fd / 48;            // 0..31
                    const int j  = fd - t * 48;        // 0,4,...,44 (never straddles)
                    const f32x4 v = *(const f32x4*)&hs[t * HSTR + j];
                    *(f32x4*)&dst[t * 200 + j] = v;
                }
            }
            if (jt == 6) {
                // flush2: j in [48,100) x 32 tokens = 1664 dwords, 7 wave-stores
                float* dst = out + (size_t)tok_base * 200 + d * 100 + 48;
                #pragma unroll
                for (int it = 0; it < 7; ++it) {
                    const int fd = it * 256 + lane * 4;
                    if (fd < 1664) {
                        const int t = fd / 52;         // 0..31
                        const int j = fd - t * 52;     // 0,4,...,48
                        const f32x4 v = *(const f32x4*)&hs[t * HSTR + j];
                        *(f32x4*)&dst[t * 200 + j] = v;
                    }
                }
            }
        }
    }
}

extern "C" void kernel_launch(void* const* d_in, const int* in_sizes, int n_in,
                              void* d_out, int out_size, void* d_ws, size_t ws_size,
                              hipStream_t stream) {
    (void)in_sizes; (void)n_in; (void)out_size; (void)ws_size;
    bf16x8* bfrag = (bf16x8*)d_ws;                       // 172032 B
    float*  bias3 = (float*)((char*)d_ws + 172032);      // 2688 B
    build_b<<<dim3(42), dim3(256), 0, stream>>>(
        (const float*)d_in[4], (const float*)d_in[5], (const float*)d_in[6],
        (const float*)d_in[7], (const float*)d_in[8], (const float*)d_in[9],
        bfrag, bias3);
    lstm_main<<<dim3(NTOK / 128), dim3(256), 0, stream>>>(
        (const int*)d_in[0], (const int*)d_in[1],
        (const float*)d_in[2], (const float*)d_in[3],
        bfrag, bias3, (float*)d_out);
}

// Round 10
// 107.672 us; speedup vs baseline: 2.3775x; 2.3775x over previous
//
#include <hip/hip_runtime.h>

typedef short bf16x8 __attribute__((ext_vector_type(8)));
typedef float f32x4 __attribute__((ext_vector_type(4)));

#define NTOK 262144
#define HH 100
#define DW 100
#define DT 25
#define KK 125

__device__ __forceinline__ short f2bf(float f) {
    union { float f; unsigned u; } v; v.f = f;
    unsigned u = v.u + 0x7FFFu + ((v.u >> 16) & 1u);   // RNE bf16 (inputs finite)
    return (short)(u >> 16);
}

__device__ __forceinline__ float sigm(float x) {
    return __builtin_amdgcn_rcpf(1.f + __expf(-x));
}
__device__ __forceinline__ float tanh_(float x) {
    return 2.f * __builtin_amdgcn_rcpf(1.f + __expf(-2.f * x)) - 1.f;
}

// ---------------- pre-kernel: build B fragments + folded biases in ws ----------------
// bfrag layout: [sid(14 = d*7+jt)][fid(12 = gt*4+ks)][lane(64)] bf16x8  (= 172032 B)
// bias3 layout: [d(2)][gt(3)][jpad(112)] float                          (= 2688 B)
__global__ __launch_bounds__(256)
void build_b(const float* __restrict__ Wf, const float* __restrict__ bif, const float* __restrict__ bhf,
             const float* __restrict__ Wb, const float* __restrict__ bib, const float* __restrict__ bhb,
             bf16x8* __restrict__ bfrag, float* __restrict__ bias3)
{
    const int gwid = (blockIdx.x * 256 + threadIdx.x) >> 6;   // 0..167
    const int lane = threadIdx.x & 63;
    if (gwid >= 168) return;
    const int d   = gwid / 84;
    const int rem = gwid % 84;           // jt*12 + fid
    const int jt  = rem / 12, fid = rem % 12;
    const int gt  = fid >> 2, ks = fid & 3;
    const int l15 = lane & 15, lg = lane >> 4;
    const int j = jt * 16 + l15;
    const bool jv = (j < HH);
    const float* W = d ? Wb : Wf;
    const int gbase = (gt == 0) ? 0 : (gt == 1) ? 2 * HH : 3 * HH;   // i, g, o (f dead: c0==0)
    const float* wrow = W + (size_t)(gbase + (jv ? j : 0)) * KK;
    bf16x8 f;
    #pragma unroll
    for (int e = 0; e < 8; ++e) {
        const int k = ks * 32 + lg * 8 + e;
        const float v = (jv && k < KK) ? wrow[k] : 0.f;
        f[e] = f2bf(v);
    }
    bfrag[(size_t)gwid * 64 + lane] = f;
    if (ks == 0 && lg == 0) {
        const float* bi = d ? bib : bif;
        const float* bh = d ? bhb : bhf;
        bias3[(d * 3 + gt) * 112 + jt * 16 + l15] =
            jv ? (bi[gbase + j] + bh[gbase + j]) : 0.f;
    }
}

// ---------------- main kernel: R6 structure + register-dbuf W prefetch ----------------
// 4 waves x 32 tokens per block (128 tokens), grid 2048; ZERO barriers.
// Flat 14-phase loop (p = d*7+jt). Even phases consume bA and prefetch bB for
// p+1; odd phases the reverse (T14: next slab's 12 L2 loads issue before the
// current phase's MFMA+epilogue -> L2 latency hidden; R6 exposed it serially).
// hstage + full-400B-island flush kept exactly as R6 (R9 proved split flushes
// trigger HBM RMW: WRITE 468 MB / FETCH +270 MB; full-island = 1.07x ideal).
__global__ __launch_bounds__(256, 3)
void lstm_main(const int* __restrict__ sent, const int* __restrict__ tags,
               const float* __restrict__ Ew, const float* __restrict__ Et,
               const bf16x8* __restrict__ bfrag, const float* __restrict__ bias3,
               float* __restrict__ out)
{
    __shared__ float hstage[4][32 * 100];   // 51200 B, per-wave private
    const int tid  = threadIdx.x;
    const int lane = tid & 63;
    const int wave = tid >> 6;
    const int l15  = lane & 15;        // token within 16-tile
    const int lg   = lane >> 4;        // k-group (inputs) / j-quad (output)
    const int kb0  = lg * 8;
    const int tok_base = blockIdx.x * 128 + wave * 32;

    // ---- gather x fragments (MFMA B-operand): x = [E_w row | E_t row | pad] ----
    bf16x8 a[2][4];
    #pragma unroll
    for (int mt = 0; mt < 2; ++mt) {
        const int tok = tok_base + mt * 16 + l15;
        const float* ew = Ew + (size_t)sent[tok] * DW;
        const float* et = Et + (size_t)tags[tok] * DT;
        #pragma unroll
        for (int ks = 0; ks < 3; ++ks) {          // k in [0,96): pure E_w, 16B-aligned
            const float* p = ew + ks * 32 + kb0;
            const float4 v0 = *(const float4*)p;
            const float4 v1 = *(const float4*)(p + 4);
            bf16x8 f;
            f[0] = f2bf(v0.x); f[1] = f2bf(v0.y); f[2] = f2bf(v0.z); f[3] = f2bf(v0.w);
            f[4] = f2bf(v1.x); f[5] = f2bf(v1.y); f[6] = f2bf(v1.z); f[7] = f2bf(v1.w);
            a[mt][ks] = f;
        }
        {   // ks == 3: k in [96,128) -> E_w tail / E_t / zero pad
            float v[8];
            if (lg == 0) {
                const float4 w = *(const float4*)(ew + 96);
                v[0] = w.x; v[1] = w.y; v[2] = w.z; v[3] = w.w;
                #pragma unroll
                for (int e = 0; e < 4; ++e) v[4 + e] = et[e];
            } else {
                const int base = lg * 8 - 4;       // E_t index of elem 0
                #pragma unroll
                for (int e = 0; e < 8; ++e) {
                    const int ti = base + e;
                    v[e] = (ti < DT) ? et[ti] : 0.f;
                }
            }
            bf16x8 f;
            #pragma unroll
            for (int e = 0; e < 8; ++e) f[e] = f2bf(v[e]);
            a[mt][3] = f;
        }
    }

    float* hs = hstage[wave];

    // one phase: MFMA (3 gates x 2 m-tiles) + LSTM epilogue + staged store;
    // full-island flush at jt==6. p is a compile-time constant at every call
    // site (loop fully unrolled), so all indexing stays static.
    auto phase = [&](const int p, const bf16x8* b) {
        const int d = p / 7, jt = p % 7;
        f32x4 acc[2][3];
        #pragma unroll
        for (int gt = 0; gt < 3; ++gt) {
            // bias pre-folded into accumulator init (row = j = jt*16+lg*4+r)
            const f32x4 bv = *(const f32x4*)&bias3[(size_t)(d * 3 + gt) * 112 + jt * 16 + lg * 4];
            acc[0][gt] = bv;
            acc[1][gt] = bv;
            #pragma unroll
            for (int mt = 0; mt < 2; ++mt)
                #pragma unroll
                for (int ks = 0; ks < 4; ++ks)
                    acc[mt][gt] = __builtin_amdgcn_mfma_f32_16x16x32_bf16(
                        b[gt * 4 + ks], a[mt][ks], acc[mt][gt], 0, 0, 0);
        }

        const bool sv = (jt < 6) || (lg == 0);   // j-quad valid (j<100)
        if (sv) {
            #pragma unroll
            for (int mt = 0; mt < 2; ++mt) {
                f32x4 h;
                #pragma unroll
                for (int r = 0; r < 4; ++r) {
                    const float c = sigm(acc[mt][0][r]) * tanh_(acc[mt][1][r]);
                    h[r] = sigm(acc[mt][2][r]) * tanh_(c);
                }
                // packed staging: [token(32)][j(100)] f32
                *(f32x4*)&hs[(mt * 16 + l15) * 100 + jt * 16 + lg * 4] = h;
            }
        }

        if (jt == 6) {
            // dense flush: 32 tokens x full 400B islands, ~1KB per wave-store
            float* dst = out + (size_t)tok_base * 200 + d * 100;
            #pragma unroll
            for (int it = 0; it < 13; ++it) {
                const int fd = it * 256 + lane * 4;     // dword offset, packed space
                if (fd < 3200) {
                    const int t = fd / 100;             // token (magic-mul)
                    const f32x4 v = *(const f32x4*)&hs[fd];
                    *(f32x4*)&dst[fd + t * 100] = v;    // = dst[t*200 + (fd - t*100)]
                }
            }
        }
    };

    bf16x8 bA[12], bB[12];
    {   // prologue: slab 0
        const bf16x8* bp = bfrag + lane;
        #pragma unroll
        for (int f = 0; f < 12; ++f) bA[f] = bp[(size_t)f * 64];
    }

    #pragma unroll
    for (int ph = 0; ph < 14; ph += 2) {
        {   // prefetch slab ph+1 (always exists: ph <= 12)
            const bf16x8* bp = bfrag + (size_t)(ph + 1) * 768 + lane;
            #pragma unroll
            for (int f = 0; f < 12; ++f) bB[f] = bp[(size_t)f * 64];
        }
        phase(ph, bA);
        if (ph + 2 < 14) {   // prefetch slab ph+2
            const bf16x8* bp = bfrag + (size_t)(ph + 2) * 768 + lane;
            #pragma unroll
            for (int f = 0; f < 12; ++f) bA[f] = bp[(size_t)f * 64];
        }
        phase(ph + 1, bB);
    }
}

extern "C" void kernel_launch(void* const* d_in, const int* in_sizes, int n_in,
                              void* d_out, int out_size, void* d_ws, size_t ws_size,
                              hipStream_t stream) {
    (void)in_sizes; (void)n_in; (void)out_size; (void)ws_size;
    bf16x8* bfrag = (bf16x8*)d_ws;                       // 172032 B
    float*  bias3 = (float*)((char*)d_ws + 172032);      // 2688 B
    build_b<<<dim3(42), dim3(256), 0, stream>>>(
        (const float*)d_in[4], (const float*)d_in[5], (const float*)d_in[6],
        (const float*)d_in[7], (const float*)d_in[8], (const float*)d_in[9],
        bfrag, bias3);
    lstm_main<<<dim3(NTOK / 128), dim3(256), 0, stream>>>(
        (const int*)d_in[0], (const int*)d_in[1],
        (const float*)d_in[2], (const float*)d_in[3],
        bfrag, bias3, (float*)d_out);
}